// Round 2
// baseline (697.613 us; speedup 1.0000x reference)
//
#include <hip/hip_runtime.h>
#include <hip/hip_bf16.h>

typedef __bf16 bf16;
typedef bf16 bf16x8 __attribute__((ext_vector_type(8)));
typedef float f32x4 __attribute__((ext_vector_type(4)));

#define D 128
#define EGRID 512

// ---------- setup: node MLP + V1 transpose + edge compact + zero signal ----------
__global__ __launch_bounds__(256) void setup_kernel(
    const float* __restrict__ x, const float* __restrict__ W1,
    const float* __restrict__ b1, const float* __restrict__ W2,
    const float* __restrict__ b2, const float* __restrict__ V1,
    const int* __restrict__ ei, int E, int bs,
    bf16* __restrict__ V1t, int* __restrict__ count, int* __restrict__ list,
    float* __restrict__ signal, float* __restrict__ logits,
    int NN, int NT, int NC)
{
  __shared__ struct { bf16 A[64][136]; bf16 W[128][136]; float o0[64]; float o1[64]; } sm;
  int bid = blockIdx.x, tid = threadIdx.x;

  if (bid < NN) {
    // ---- node path: logits = relu(x@W1+b1)@W2 + b2, rows bid*64.. ----
    // stage W1 (row-major [k][n]) -> sm.W[n][k] bf16, via 4x4 micro-tiles
#pragma unroll
    for (int p = 0; p < 4; ++p) {
      int tile = tid + p * 256;            // 0..1023 = 32x32 tiles
      int tk = tile >> 5, tn = tile & 31;
      float4 r0 = *(const float4*)&W1[(4 * tk + 0) * D + 4 * tn];
      float4 r1 = *(const float4*)&W1[(4 * tk + 1) * D + 4 * tn];
      float4 r2 = *(const float4*)&W1[(4 * tk + 2) * D + 4 * tn];
      float4 r3 = *(const float4*)&W1[(4 * tk + 3) * D + 4 * tn];
      const float* q0 = (const float*)&r0; const float* q1 = (const float*)&r1;
      const float* q2 = (const float*)&r2; const float* q3 = (const float*)&r3;
#pragma unroll
      for (int j = 0; j < 4; ++j) {
        union { bf16 h[4]; ushort4 u; } cv;
        cv.h[0] = (bf16)q0[j]; cv.h[1] = (bf16)q1[j];
        cv.h[2] = (bf16)q2[j]; cv.h[3] = (bf16)q3[j];
        *(ushort4*)&sm.W[4 * tn + j][4 * tk] = cv.u;
      }
    }
    {  // stage 64 node rows fp32 -> bf16
      int g = tid >> 5, fl = tid & 31;
#pragma unroll
      for (int i = 0; i < 8; ++i) {
        int row = i * 8 + g;
        const float4* base = (const float4*)(x + (size_t)(bid * 64 + row) * D);
        float4 v = base[fl];
        union { bf16 h[4]; uint2 u; } cv;
        cv.h[0] = (bf16)v.x; cv.h[1] = (bf16)v.y; cv.h[2] = (bf16)v.z; cv.h[3] = (bf16)v.w;
        *(uint2*)&sm.A[row][fl * 4] = cv.u;
      }
    }
    if (tid < 64) { sm.o0[tid] = 0.f; sm.o1[tid] = 0.f; }
    __syncthreads();

    int wave = tid >> 6, lane = tid & 63;
    int l15 = lane & 15, quad = lane >> 4;
    f32x4 acc[2][4];
#pragma unroll
    for (int ct = 0; ct < 2; ++ct)
#pragma unroll
      for (int rt = 0; rt < 4; ++rt) acc[ct][rt] = (f32x4){0.f, 0.f, 0.f, 0.f};
    for (int kc = 0; kc < 4; ++kc) {
      int k = kc * 32 + quad * 8;
      bf16x8 a[4], b[2];
#pragma unroll
      for (int rt = 0; rt < 4; ++rt) a[rt] = *(const bf16x8*)&sm.A[rt * 16 + l15][k];
#pragma unroll
      for (int ct = 0; ct < 2; ++ct) b[ct] = *(const bf16x8*)&sm.W[wave * 32 + ct * 16 + l15][k];
#pragma unroll
      for (int ct = 0; ct < 2; ++ct)
#pragma unroll
        for (int rt = 0; rt < 4; ++rt)
          acc[ct][rt] = __builtin_amdgcn_mfma_f32_16x16x32_bf16(a[rt], b[ct], acc[ct][rt], 0, 0, 0);
    }
    float bc[2], w0[2], w1[2];
#pragma unroll
    for (int ct = 0; ct < 2; ++ct) {
      int n = wave * 32 + ct * 16 + l15;
      bc[ct] = b1[n]; w0[ct] = W2[n * 2]; w1[ct] = W2[n * 2 + 1];
    }
#pragma unroll
    for (int rt = 0; rt < 4; ++rt) {
#pragma unroll
      for (int reg = 0; reg < 4; ++reg) {
        float p0 = 0.f, p1 = 0.f;
#pragma unroll
        for (int ct = 0; ct < 2; ++ct) {
          float h = fmaxf(acc[ct][rt][reg] + bc[ct], 0.f);
          p0 += h * w0[ct]; p1 += h * w1[ct];
        }
        p0 += __shfl_xor(p0, 1, 16); p0 += __shfl_xor(p0, 2, 16);
        p0 += __shfl_xor(p0, 4, 16); p0 += __shfl_xor(p0, 8, 16);
        p1 += __shfl_xor(p1, 1, 16); p1 += __shfl_xor(p1, 2, 16);
        p1 += __shfl_xor(p1, 4, 16); p1 += __shfl_xor(p1, 8, 16);
        if (l15 == 0) {
          int row = rt * 16 + quad * 4 + reg;
          atomicAdd(&sm.o0[row], p0);
          atomicAdd(&sm.o1[row], p1);
        }
      }
    }
    __syncthreads();
    if (tid < 64) {
      int node = bid * 64 + tid;
      if (node < bs) {
        logits[2 * node]     = sm.o0[tid] + b2[0];
        logits[2 * node + 1] = sm.o1[tid] + b2[1];
      }
    }
  } else if (bid < NN + NT) {
    int i = (bid - NN) * 256 + tid;        // exactly covers 384*384
    int k = i / 384, n = i - k * 384;
    V1t[n * 384 + k] = (bf16)V1[i];
  } else if (bid < NN + NT + NC) {
    int e = (bid - NN - NT) * 256 + tid;
    if (e < E && ei[e] < bs) { int p = atomicAdd(count, 1); list[p] = e; }
  } else {
    int i = (bid - NN - NT - NC) * 256 + tid;
    if (i < bs) signal[i] = 0.f;
  }
}

// ---------- edge MLP + sigmoid + segment_max: persistent, pipelined ----------
__global__ __launch_bounds__(256, 2) void edge_kernel(
    const float* __restrict__ x, const float* __restrict__ ea,
    const bf16* __restrict__ V1t, const float* __restrict__ bv1,
    const float* __restrict__ V2, const float* __restrict__ bv2,
    const int* __restrict__ ei, const int* __restrict__ count,
    const int* __restrict__ list, float* __restrict__ signal,
    int E, int bs)
{
  __shared__ bf16 sA[64][392];          // 50176 B (pad 8: 2-way alias free)
  __shared__ int sIdx[2][3][64];        // [slot][src,dst,e][row]
  __shared__ float sScore[64];

  const int live = *count;
  const int nT = (live + 63) >> 6;
  const int bid0 = blockIdx.x;
  if (bid0 >= nT) return;               // uniform, before any barrier
  const int stride = gridDim.x;
  const int tid = threadIdx.x;
  const int g = tid >> 5, fl = tid & 31;

  // prologue: slots 0/1 <- idx(t0), idx(t0+stride); eReg <- list(t0+2*stride)
  if (tid < 64) sScore[tid] = 0.f;
  if (tid < 128) {
    int slot = tid >> 6, r = tid & 63;
    int tt = bid0 + slot * stride;
    int e = 0, s = 0, d = 0;
    if (tt < nT) {
      int gi = tt * 64 + r;
      if (gi < live) { e = list[gi]; s = ei[e]; d = ei[E + e]; }
    }
    sIdx[slot][0][r] = s; sIdx[slot][1][r] = d; sIdx[slot][2][r] = e;
  }
  int eReg = 0;
  {
    int t2 = bid0 + 2 * stride;
    if (tid < 64 && t2 < nT) {
      int gi = t2 * 64 + tid;
      if (gi < live) eReg = list[gi];
    }
  }
  __syncthreads();

  // issue ea-gather(t0): 8 float4/thread (64 rows x 32 f4)
  float4 Rea[8];
#pragma unroll
  for (int i = 0; i < 8; ++i) {
    int r = i * 8 + g;
    int e = sIdx[0][2][r];
    Rea[i] = ((const float4*)(ea + (size_t)e * D))[fl];
  }

  const int wave = tid >> 6, lane = tid & 63;
  const int l15 = lane & 15, quad = lane >> 4;
  const bf16* Bbase = V1t + (size_t)(wave * 96 + l15) * 384 + quad * 8;
  float bvc[6], v2c[6];
#pragma unroll
  for (int ct = 0; ct < 6; ++ct) {
    int n = wave * 96 + ct * 16 + l15;
    bvc[ct] = bv1[n]; v2c[ct] = V2[n];
  }

  int it = 0;
  for (int t = bid0; t < nT; t += stride, ++it) {
    const int P = it & 1;
    const bool hasN = (t + stride) < nT;
    const bool has2 = (t + 2 * stride) < nT;
    const bool has3 = (t + 3 * stride) < nT;

    __syncthreads();   // B1: sA free (prev MFMA done), slot[P] visible

    // convert Rea(t) -> sA seg2 (ea in flight since last iter: already done)
#pragma unroll
    for (int i = 0; i < 8; ++i) {
      int r = i * 8 + g;
      union { bf16 h[4]; uint2 u; } cv;
      cv.h[0] = (bf16)Rea[i].x; cv.h[1] = (bf16)Rea[i].y;
      cv.h[2] = (bf16)Rea[i].z; cv.h[3] = (bf16)Rea[i].w;
      *(uint2*)&sA[r][256 + fl * 4] = cv.u;
    }
    // issue x-gathers(t): 16 f4/thread (L2/L3-hot)
    float4 Rx[16];
#pragma unroll
    for (int i = 0; i < 16; ++i) {
      int tt2 = i * 8 + g;
      int r = tt2 & 63, seg = tt2 >> 6;
      int idx = sIdx[P][seg][r];
      Rx[i] = ((const float4*)(x + (size_t)idx * D))[fl];
    }
    // issue ea-gather(t+1) NOW: stays in flight through the whole MFMA phase
    if (hasN) {
#pragma unroll
      for (int i = 0; i < 8; ++i) {
        int r = i * 8 + g;
        int e = sIdx[P ^ 1][2][r];
        Rea[i] = ((const float4*)(ea + (size_t)e * D))[fl];
      }
    }
    // index pipeline: sd(t+2) from eReg; list(t+3) -> eReg
    int sN = 0, dN = 0, eSv = eReg;
    if (tid < 64) {
      if (has2) { sN = ei[eSv]; dN = ei[E + eSv]; }
      eReg = 0;
      if (has3) {
        int gi = (t + 3 * stride) * 64 + tid;
        if (gi < live) eReg = list[gi];
      }
    }
    int srcCur = sIdx[P][0][tid & 63];
    // convert x -> sA seg0/1 (waits only Rx: vmcnt leaves ea stream flying)
#pragma unroll
    for (int i = 0; i < 16; ++i) {
      int tt2 = i * 8 + g;
      int r = tt2 & 63, seg = tt2 >> 6;
      union { bf16 h[4]; uint2 u; } cv;
      cv.h[0] = (bf16)Rx[i].x; cv.h[1] = (bf16)Rx[i].y;
      cv.h[2] = (bf16)Rx[i].z; cv.h[3] = (bf16)Rx[i].w;
      *(uint2*)&sA[r][seg * 128 + fl * 4] = cv.u;
    }
    __syncthreads();   // B2: sA ready

    f32x4 acc[6][4];
#pragma unroll
    for (int ct = 0; ct < 6; ++ct)
#pragma unroll
      for (int rt = 0; rt < 4; ++rt) acc[ct][rt] = (f32x4){0.f, 0.f, 0.f, 0.f};

    bf16x8 bCur[6], bNxt[6];
#pragma unroll
    for (int ct = 0; ct < 6; ++ct)
      bCur[ct] = *(const bf16x8*)(Bbase + (size_t)ct * 16 * 384);
    for (int kc = 0; kc < 12; ++kc) {
      bf16x8 a[4];
      int k = kc * 32 + quad * 8;
#pragma unroll
      for (int rt = 0; rt < 4; ++rt)
        a[rt] = *(const bf16x8*)&sA[rt * 16 + l15][k];
      if (kc < 11) {
#pragma unroll
        for (int ct = 0; ct < 6; ++ct)
          bNxt[ct] = *(const bf16x8*)(Bbase + (size_t)ct * 16 * 384 + (kc + 1) * 32);
      }
#pragma unroll
      for (int ct = 0; ct < 6; ++ct)
#pragma unroll
        for (int rt = 0; rt < 4; ++rt)
          acc[ct][rt] = __builtin_amdgcn_mfma_f32_16x16x32_bf16(a[rt], bCur[ct], acc[ct][rt], 0, 0, 0);
#pragma unroll
      for (int ct = 0; ct < 6; ++ct) bCur[ct] = bNxt[ct];
    }

    // epilogue: +bv1, relu, dot V2, reduce across l15, accumulate per-row
#pragma unroll
    for (int rt = 0; rt < 4; ++rt) {
#pragma unroll
      for (int reg = 0; reg < 4; ++reg) {
        float p = 0.f;
#pragma unroll
        for (int ct = 0; ct < 6; ++ct)
          p += fmaxf(acc[ct][rt][reg] + bvc[ct], 0.f) * v2c[ct];
        p += __shfl_xor(p, 1, 16); p += __shfl_xor(p, 2, 16);
        p += __shfl_xor(p, 4, 16); p += __shfl_xor(p, 8, 16);
        if (l15 == 0) atomicAdd(&sScore[rt * 16 + quad * 4 + reg], p);
      }
    }
    // park idx(t+2) into slot[P] (free: this iter's reads of slot[P] ended pre-B2)
    if (tid < 64 && has2) {
      sIdx[P][0][tid] = sN; sIdx[P][1][tid] = dN; sIdx[P][2][tid] = eSv;
    }
    __syncthreads();   // B3: sScore complete
    if (tid < 64) {
      if ((t * 64 + tid) < live) {
        float sc = sScore[tid] + bv2[0];
        float sig = 1.f / (1.f + __expf(-sc));
        // sigmoid > 0, signal init 0: positive-float int compare == float max
        atomicMax((int*)&signal[srcCur], __float_as_int(sig));
      }
      sScore[tid] = 0.f;
    }
  }
}

// ---------------- combine + labels ----------------
__global__ void combine_kernel(const float* __restrict__ logits, const float* __restrict__ signal,
                               const int* __restrict__ y, const float* __restrict__ ecw,
                               float* __restrict__ out, int bs) {
  int i = blockIdx.x * 256 + threadIdx.x;
  if (i < bs) {
    out[2 * i]      = logits[2 * i];
    out[2 * i + 1]  = logits[2 * i + 1] + ecw[0] * signal[i];
    out[2 * bs + i] = (float)y[i];
  }
}

extern "C" void kernel_launch(void* const* d_in, const int* in_sizes, int n_in,
                              void* d_out, int out_size, void* d_ws, size_t ws_size,
                              hipStream_t stream) {
  const float* x   = (const float*)d_in[0];
  const float* ea  = (const float*)d_in[1];
  const float* W1  = (const float*)d_in[2];
  const float* b1  = (const float*)d_in[3];
  const float* W2  = (const float*)d_in[4];
  const float* b2  = (const float*)d_in[5];
  const float* V1  = (const float*)d_in[6];
  const float* bv1 = (const float*)d_in[7];
  const float* V2  = (const float*)d_in[8];
  const float* bv2 = (const float*)d_in[9];
  const float* ecw = (const float*)d_in[10];
  const int*   ei  = (const int*)d_in[11];
  const int*   y   = (const int*)d_in[12];

  int E  = in_sizes[1] / D;
  int bs = out_size / 3;          // 2*bs logits + bs labels

  char* ws = (char*)d_ws;
  size_t off = 0;
  bf16* V1t = (bf16*)(ws + off); off += (size_t)384 * 384 * 2;
  float* signal = (float*)(ws + off); off += (size_t)bs * 4;
  float* logits = (float*)(ws + off); off += (size_t)bs * 8;
  int* count = (int*)(ws + off); off += 16;
  int* list  = (int*)(ws + off); off += (size_t)E * 4;

  int NN = (bs + 63) / 64;        // node blocks (first: longest path)
  int NT = (384 * 384) / 256;     // transpose blocks
  int NC = (E + 255) / 256;       // compact blocks
  int NZ = (bs + 255) / 256;      // signal-zero blocks

  hipMemsetAsync(count, 0, 4, stream);
  setup_kernel<<<NN + NT + NC + NZ, 256, 0, stream>>>(
      x, W1, b1, W2, b2, V1, ei, E, bs, V1t, count, list, signal, logits, NN, NT, NC);
  edge_kernel<<<EGRID, 256, 0, stream>>>(x, ea, V1t, bv1, V2, bv2,
                                         ei, count, list, signal, E, bs);
  combine_kernel<<<(bs + 255) / 256, 256, 0, stream>>>(logits, signal, y, ecw,
                                                       (float*)d_out, bs);
}